// Round 11
// baseline (174.678 us; speedup 1.0000x reference)
//
#include <hip/hip_runtime.h>
#include <math.h>

#define NROWS 2400
#define NCLS  91
#define L     128
#define KSUB  23
#define NKEEP 256
#define STR   40    // ushort row stride: 80B -> 16B-aligned, 2-way banks (free)

typedef short  bf16x8 __attribute__((ext_vector_type(8)));   // 8 bf16 = 4 VGPRs
typedef float  f32x4  __attribute__((ext_vector_type(4)));

// LDS byte layout:
// [0,     10240)  Ctb[128][STR] ushort : Ctb[i][k] = bf16(C[k][i]); k in [23,40) zero
// [10240, 12800)  A1 [32][STR]  ushort : A1[v][u] = bf16(coef[u][v]); zero elsewhere
// [12800, 23040)  Ab [128][STR] ushort : Ab[i][v] = bf16(M1t[v][i])
// [23040, 23104)  red[16] float
#define CTB_OFF  0
#define A1_OFF   10240
#define ABUF_OFF 12800
#define RED_OFF  23040
#define SMEM_BYTES 23104

__device__ __forceinline__ unsigned short f2bf(float f) {
    unsigned int u = __float_as_uint(f);
    unsigned int r = u + 0x7fffu + ((u >> 16) & 1u);   // round-to-nearest-even
    return (unsigned short)(r >> 16);
}

__global__ void __launch_bounds__(512)
postproc_kernel(const float* __restrict__ logits,
                const float* __restrict__ pboxes,
                const float* __restrict__ vecs,
                const int*   __restrict__ tsz,
                float* __restrict__ out)
{
    __shared__ __align__(16) unsigned char sm[SMEM_BYTES];
    unsigned short* Ctb = (unsigned short*)(sm + CTB_OFF);
    unsigned short* A1  = (unsigned short*)(sm + A1_OFF);
    unsigned short* Ab  = (unsigned short*)(sm + ABUF_OFF);
    float*          red = (float*)(sm + RED_OFF);

    const int br  = blockIdx.x;
    const int tid = threadIdx.x;

    // ---------- Part A: scores / labels / boxes (wave 0 only; exact fp32 path) ----------
    if (tid < 64) {
        const float* lrow = logits + (size_t)br * NCLS;
        float p = 1.0f / (1.0f + expf(-lrow[tid]));
        int   bi = tid;
        if (tid < NCLS - 64) {
            float p2 = 1.0f / (1.0f + expf(-lrow[tid + 64]));
            if (p2 > p) { p = p2; bi = tid + 64; }    // tie -> keep lower index
        }
        #pragma unroll
        for (int off = 32; off > 0; off >>= 1) {
            float po = __shfl_xor(p, off, 64);
            int   io = __shfl_xor(bi, off, 64);
            if (po > p || (po == p && io < bi)) { p = po; bi = io; }
        }
        if (tid == 0) {
            out[br] = p;
            out[NROWS + br] = (float)bi;
            const int b = br / 300;
            const float W = (float)tsz[2 * b + 1];
            const float H = (float)tsz[2 * b + 0];
            const float4 bx = *(const float4*)(pboxes + (size_t)br * 4);
            float4 o;
            o.x = (bx.x - 0.5f * bx.z) * W;
            o.y = (bx.y - 0.5f * bx.w) * H;
            o.z = (bx.x + 0.5f * bx.z) * W;
            o.w = (bx.y + 0.5f * bx.w) * H;
            *(float4*)(out + 2 * NROWS + (size_t)br * 4) = o;
        }
    }

    // ---------- Single staging phase: Ctb build (f32 cos), A1 complement-zero, scatter ----------
    {
        const float s0 = 0.08838834764831845f;           // sqrt(1/128)
        for (int idx = tid; idx < 128 * 32; idx += 512) {
            const int i = idx >> 5, k = idx & 31;
            float v;
            if (k == 0)       v = s0;
            else if (k < 23) {
                const int t = ((2 * i + 1) * k) & 511;   // exact integer phase, period 512
                v = 0.125f * __cosf((float)t * 0.012271846303085129f);  // pi/256
            } else            v = 0.0f;
            Ctb[i * STR + k] = f2bf(v);
        }
        for (int idx = tid; idx < 128 * 4; idx += 512) { // zero pad cols k in [32,40)
            const int i = idx >> 2, q = idx & 3;
            ((unsigned int*)(Ctb + i * STR + 32))[q] = 0u;
        }
    }
    for (int idx = tid; idx < 32 * STR; idx += 512) {    // A1 complement-zero
        const int vv = idx / STR, u = idx - vv * STR;
        const int s = u + vv;
        if (s > 22 || (s == 22 && u < 20)) A1[idx] = 0;
    }
    if (tid < NKEEP) {
        const int k = tid;
        int s = 0;
        while ((s + 1) * (s + 2) / 2 <= k) ++s;          // zigzag diagonal, s <= 22
        const int r = k - s * (s + 1) / 2;
        const int u  = (s & 1) ? r : (s - r);
        const int vv = (s & 1) ? (s - r) : r;
        A1[vv * STR + u] = f2bf(vecs[(size_t)br * NKEEP + k]);
    }
    __syncthreads();

    const int w  = tid >> 6;                             // wave id 0..7 (uniform)
    const int ml = tid & 15;
    const int kq = (tid & 63) >> 4;                      // quad 0..3

    // ---------- Stage 1 MFMA: D1[v][i] = sum_u A1[v][u] * C[u][i] -> Ab[i][v] (bf16) ----------
    {
        const f32x4 cz = {0.0f, 0.0f, 0.0f, 0.0f};
        #pragma unroll
        for (int p = 0; p < 2; ++p) {
            const int idx = 2 * w + p;                   // 16 tiles: tr in {0,1}, tc in 0..7
            const int tr = idx >> 3, tc = idx & 7;
            bf16x8 a1 = *(const bf16x8*)(A1  + (tr * 16 + ml) * STR + kq * 8);
            bf16x8 b1 = *(const bf16x8*)(Ctb + (tc * 16 + ml) * STR + kq * 8);
            f32x4 d1 = __builtin_amdgcn_mfma_f32_16x16x32_bf16(a1, b1, cz, 0, 0, 0);
            #pragma unroll
            for (int r = 0; r < 4; ++r)
                Ab[(tc * 16 + ml) * STR + tr * 16 + kq * 4 + r] = f2bf(d1[r]);
        }
    }
    __syncthreads();

    // ---------- Stage 2 MFMA (operands SWAPPED -> transposed tiles) ----------
    // acc[s] = mfma(A = Ctb rows s*16+ml (cols j of mask), B = Ab rows w*16+ml (rows i)):
    // D[j'][i'] with j' = kq*4 + r (consecutive mask cols!), i' = ml.
    f32x4 acc[8];
    {
        const f32x4 cz = {0.0f, 0.0f, 0.0f, 0.0f};
        bf16x8 b2 = *(const bf16x8*)(Ab + (w * 16 + ml) * STR + kq * 8);
        #pragma unroll
        for (int s = 0; s < 8; ++s) {
            bf16x8 a2 = *(const bf16x8*)(Ctb + (s * 16 + ml) * STR + kq * 8);
            acc[s] = __builtin_amdgcn_mfma_f32_16x16x32_bf16(a2, b2, cz, 0, 0, 0);
        }
    }

    // ---------- min/max reduce -> threshold (same value set as before) ----------
    float mn = acc[0][0], mx = acc[0][0];
    #pragma unroll
    for (int s = 0; s < 8; ++s)
        #pragma unroll
        for (int r = 0; r < 4; ++r) {
            mn = fminf(mn, acc[s][r]);
            mx = fmaxf(mx, acc[s][r]);
        }
    #pragma unroll
    for (int off = 32; off > 0; off >>= 1) {
        mn = fminf(mn, __shfl_xor(mn, off, 64));
        mx = fmaxf(mx, __shfl_xor(mx, off, 64));
    }
    if ((tid & 63) == 0) { red[w] = mn; red[8 + w] = mx; }
    __syncthreads();
    float gmn = red[0], gmx = red[8];
    #pragma unroll
    for (int k = 1; k < 8; ++k) {
        gmn = fminf(gmn, red[k]);
        gmx = fmaxf(gmx, red[8 + k]);
    }
    const float thr = (gmx + gmn) * 0.5f;

    // ---------- binarize + contiguous float4 stores (row = w*16+ml, cols s*16+kq*4+{0..3}) ----------
    float* orow = out + 6 * NROWS + (size_t)br * (L * L)
                + (size_t)(w * 16 + ml) * L + kq * 4;
    #pragma unroll
    for (int s = 0; s < 8; ++s) {
        float4 o;
        o.x = acc[s][0] > thr ? 1.0f : 0.0f;
        o.y = acc[s][1] > thr ? 1.0f : 0.0f;
        o.z = acc[s][2] > thr ? 1.0f : 0.0f;
        o.w = acc[s][3] > thr ? 1.0f : 0.0f;
        *(float4*)(orow + s * 16) = o;
    }
}

extern "C" void kernel_launch(void* const* d_in, const int* in_sizes, int n_in,
                              void* d_out, int out_size, void* d_ws, size_t ws_size,
                              hipStream_t stream)
{
    const float* logits = (const float*)d_in[0];
    const float* pboxes = (const float*)d_in[1];
    const float* vecs   = (const float*)d_in[2];
    const int*   tsz    = (const int*)d_in[3];
    float* out = (float*)d_out;
    (void)d_ws; (void)ws_size; (void)in_sizes; (void)n_in; (void)out_size;

    postproc_kernel<<<dim3(NROWS), dim3(512), 0, stream>>>(logits, pboxes, vecs, tsz, out);
}